// Round 5
// baseline (360.659 us; speedup 1.0000x reference)
//
#include <hip/hip_runtime.h>
#include <math.h>

#define T_SEQ  2048
#define DMODEL 2048
#define NHEADS 16
#define HDIM   128
#define MROWS  4096   // B*T

typedef __attribute__((ext_vector_type(8)))  __bf16 bf16x8;
typedef __attribute__((ext_vector_type(4)))  __bf16 bf16x4;
typedef __attribute__((ext_vector_type(4)))  float  f32x4;
typedef __attribute__((ext_vector_type(16))) float  f32x16;

#define GLOBAL_AS __attribute__((address_space(1)))
#define LDS_AS    __attribute__((address_space(3)))
__device__ __forceinline__ void async_copy16(const __bf16* g, __bf16* l) {
  // 16B/lane, LDS dest = wave-uniform base + lane*16 (m97/m104 semantics)
  __builtin_amdgcn_global_load_lds((const GLOBAL_AS void*)g, (LDS_AS void*)l, 16, 0, 0);
}

// ---------------------------------------------------------------------------
// RoPE table: rope[pos*64+d] = {cos, sin}. fp64 trig (one-time, 131k entries).
// ---------------------------------------------------------------------------
__global__ void build_rope_kernel(float2* __restrict__ rope) {
  int idx = blockIdx.x * blockDim.x + threadIdx.x;   // 2048*64
  int d = idx & 63, pos = idx >> 6;
  double freq = pow(10000.0, -(double)d / 64.0);
  double ang = (double)pos * freq;
  rope[idx] = make_float2((float)cos(ang), (float)sin(ang));
}

// ---------------------------------------------------------------------------
// fp32 -> bf16 cast
// ---------------------------------------------------------------------------
__global__ void cast_bf16_kernel(const float* __restrict__ in,
                                 __bf16* __restrict__ out, int n4) {
  int i = blockIdx.x * blockDim.x + threadIdx.x;
  if (i >= n4) return;
  float4 v = ((const float4*)in)[i];
  bf16x4 o = { (__bf16)v.x, (__bf16)v.y, (__bf16)v.z, (__bf16)v.w };
  *(bf16x4*)(out + (size_t)i*4) = o;
}

// ---------------------------------------------------------------------------
// Combined weight transpose-cast: Wq|Wk|Wv -> wqkvt [2304][2048],
// Wo -> wot [2048][2048]. One launch, region by blockIdx.x.
// ---------------------------------------------------------------------------
__global__ void wtrans_kernel(const float* __restrict__ Wq,
                              const float* __restrict__ Wk,
                              const float* __restrict__ Wv,
                              const float* __restrict__ Wo,
                              __bf16* __restrict__ wqkvt,
                              __bf16* __restrict__ wot) {
  __shared__ float t[32][33];
  const int bx = blockIdx.x;            // 0..135
  const float* src; __bf16* dst; int istride, c0, orow;
  if (bx < 64)       { src = Wq; istride = 2048; c0 = bx*32;      orow = c0;        dst = wqkvt; }
  else if (bx < 68)  { src = Wk; istride = 128;  c0 = (bx-64)*32; orow = 2048 + c0; dst = wqkvt; }
  else if (bx < 72)  { src = Wv; istride = 128;  c0 = (bx-68)*32; orow = 2176 + c0; dst = wqkvt; }
  else               { src = Wo; istride = 2048; c0 = (bx-72)*32; orow = c0;        dst = wot; }
  const int tx = threadIdx.x & 31, ty = threadIdx.x >> 5;
  const int r0 = blockIdx.y*32;
#pragma unroll
  for (int i = 0; i < 4; ++i)
    t[ty + i*8][tx] = src[(size_t)(r0 + ty + i*8)*istride + c0 + tx];
  __syncthreads();
#pragma unroll
  for (int i = 0; i < 4; ++i)
    dst[(size_t)(orow + ty + i*8)*2048 + r0 + tx] = (__bf16)t[tx][ty + i*8];
}

// ---------------------------------------------------------------------------
// bf16 -> bf16 transpose for V: in [B][2048][128] -> out [B][128][2048].
// ---------------------------------------------------------------------------
__global__ void transpose_v_kernel(const __bf16* __restrict__ in,
                                   __bf16* __restrict__ out) {
  __shared__ __bf16 t[32][34];
  const int bz = blockIdx.z;
  in  += (size_t)bz * 2048 * 128;
  out += (size_t)bz * 128 * 2048;
  const int tx = threadIdx.x & 31, ty = threadIdx.x >> 5;
  const int r0 = blockIdx.y*32, c0 = blockIdx.x*32;
#pragma unroll
  for (int i = 0; i < 4; ++i)
    t[ty + i*8][tx] = in[(size_t)(r0 + ty + i*8)*128 + c0 + tx];
  __syncthreads();
#pragma unroll
  for (int i = 0; i < 4; ++i)
    out[(size_t)(c0 + ty + i*8)*2048 + r0 + tx] = t[tx][ty + i*8];
}

// ---------------------------------------------------------------------------
// Fused QKV GEMM: C = x @ [Wq|Wk|Wv] + bias, then RoPE (Q,K) + scale (Q) +
// bf16 cast, all register-resident in the epilogue (column remap puts the
// RoPE pair (d, d+64) in the same lane). m97-style K-loop.
// grid (18, 32): bx 0..15 = Q head bx; bx 16 = K; bx 17 = V.
// ---------------------------------------------------------------------------
__global__ __launch_bounds__(256) void gemm_qkv_fused(
    const __bf16* __restrict__ A,      // xb [4096][2048]
    const __bf16* __restrict__ Bt,     // wqkvt [2304][2048]
    const float* __restrict__ bq, const float* __restrict__ bk,
    const float* __restrict__ bv,
    const float2* __restrict__ rope,   // [2048][64]
    __bf16* __restrict__ qrb,          // [4096][2048]
    __bf16* __restrict__ kbb,          // [4096][128]
    __bf16* __restrict__ vbb,          // [4096][128]
    float qscale)
{
  __shared__ __bf16 As[128*32];
  __shared__ __bf16 Bs[128*32];
  const int tid = threadIdx.x;
  const int lane = tid & 63, wave = tid >> 6;
  const int quad = lane >> 4, l16 = lane & 15;
  const int m0 = (wave >> 1)*64, n0 = (wave & 1)*32;
  const int row0 = blockIdx.y*128, col0 = blockIdx.x*128;
  const int srow = lane >> 2, scol = (lane & 3)*8;

  f32x4 acc[4][4];
#pragma unroll
  for (int i = 0; i < 4; ++i)
#pragma unroll
    for (int j = 0; j < 4; ++j) acc[i][j] = (f32x4){0.f,0.f,0.f,0.f};

  const __bf16* Ag = A  + (size_t)(row0 + wave*32 + srow)*DMODEL + scol;
  const __bf16* Bg = Bt + (size_t)(col0 + wave*32 + srow)*DMODEL + scol;
  __bf16* AsW = &As[wave*1024];
  __bf16* BsW = &Bs[wave*1024];

  for (int kk = 0; kk < DMODEL; kk += 32) {
    __syncthreads();
    async_copy16(Ag + kk,                     AsW);
    async_copy16(Ag + kk + (size_t)16*DMODEL, AsW + 512);
    async_copy16(Bg + kk,                     BsW);
    async_copy16(Bg + kk + (size_t)16*DMODEL, BsW + 512);
    __syncthreads();
    bf16x8 af[4], bfr[4];
#pragma unroll
    for (int i = 0; i < 4; ++i)
      af[i] = *(const bf16x8*)&As[(m0 + i*16 + l16)*32 + quad*8];
#pragma unroll
    for (int j = 0; j < 4; ++j) {
      const int cb = n0 + (j & 1)*16 + (j >> 1)*64;   // remapped column base
      bfr[j] = *(const bf16x8*)&Bs[(cb + l16)*32 + quad*8];
    }
#pragma unroll
    for (int i = 0; i < 4; ++i)
#pragma unroll
      for (int j = 0; j < 4; ++j)
        acc[i][j] = __builtin_amdgcn_mfma_f32_16x16x32_bf16(af[i], bfr[j], acc[i][j], 0,0,0);
  }

  // ---- fused epilogue: bias + RoPE + scale + bf16 store -------------------
  const int bx = blockIdx.x;
  const float* bias_p; float scale; bool rot; __bf16* obase; int ostride;
  if (bx < 16)      { bias_p = bq + bx*128; scale = qscale; rot = true;
                      obase = qrb + bx*128; ostride = 2048; }
  else if (bx == 16){ bias_p = bk; scale = 1.f; rot = true;
                      obase = kbb; ostride = 128; }
  else              { bias_p = bv; scale = 1.f; rot = false;
                      obase = vbb; ostride = 128; }

#pragma unroll
  for (int j = 0; j < 2; ++j) {
    const int d = n0 + j*16 + l16;        // 0..63 within the 128-wide region
    const float b1 = bias_p[d], b2 = bias_p[d + 64];
#pragma unroll
    for (int i = 0; i < 4; ++i) {
      const int rl = m0 + i*16 + quad*4;
#pragma unroll
      for (int r = 0; r < 4; ++r) {
        const int rg = row0 + rl + r;
        const float x1 = acc[i][j][r]   + b1;
        const float x2 = acc[i][j+2][r] + b2;
        float c = 1.f, s = 0.f;
        if (rot) { float2 cs = rope[(size_t)(rg & (T_SEQ-1))*64 + d]; c = cs.x; s = cs.y; }
        obase[(size_t)rg*ostride + d]      = (__bf16)((x1*c - x2*s)*scale);
        obase[(size_t)rg*ostride + d + 64] = (__bf16)((x2*c + x1*s)*scale);
      }
    }
  }
}

// ---------------------------------------------------------------------------
// m97-style bf16 MFMA GEMM: C = A@B + bias, fp32 out (O projection).
// ---------------------------------------------------------------------------
__global__ __launch_bounds__(256) void gemm_bf16_t128(
    const __bf16* __restrict__ A, const __bf16* __restrict__ Bt,
    const float* __restrict__ bias, float* __restrict__ C,
    int M, int N, int K)
{
  __shared__ __bf16 As[128*32];
  __shared__ __bf16 Bs[128*32];
  const int tid = threadIdx.x;
  const int lane = tid & 63, wave = tid >> 6;
  const int quad = lane >> 4, l16 = lane & 15;
  const int m0 = (wave & 1)*64, n0 = (wave >> 1)*64;
  const int row0 = blockIdx.y*128, col0 = blockIdx.x*128;
  const int srow = lane >> 2, scol = (lane & 3)*8;

  f32x4 acc[4][4];
#pragma unroll
  for (int i = 0; i < 4; ++i)
#pragma unroll
    for (int j = 0; j < 4; ++j) acc[i][j] = (f32x4){0.f,0.f,0.f,0.f};

  const __bf16* Ag = A  + (size_t)(row0 + wave*32 + srow)*K + scol;
  const __bf16* Bg = Bt + (size_t)(col0 + wave*32 + srow)*K + scol;
  __bf16* AsW = &As[wave*1024];
  __bf16* BsW = &Bs[wave*1024];

  for (int kk = 0; kk < K; kk += 32) {
    __syncthreads();
    async_copy16(Ag + kk,              AsW);
    async_copy16(Ag + kk + (size_t)16*K, AsW + 512);
    async_copy16(Bg + kk,              BsW);
    async_copy16(Bg + kk + (size_t)16*K, BsW + 512);
    __syncthreads();
    bf16x8 af[4], bfr[4];
#pragma unroll
    for (int i = 0; i < 4; ++i)
      af[i] = *(const bf16x8*)&As[(m0 + i*16 + l16)*32 + quad*8];
#pragma unroll
    for (int j = 0; j < 4; ++j)
      bfr[j] = *(const bf16x8*)&Bs[(n0 + j*16 + l16)*32 + quad*8];
#pragma unroll
    for (int i = 0; i < 4; ++i)
#pragma unroll
      for (int j = 0; j < 4; ++j)
        acc[i][j] = __builtin_amdgcn_mfma_f32_16x16x32_bf16(af[i], bfr[j], acc[i][j], 0,0,0);
  }
#pragma unroll
  for (int j = 0; j < 4; ++j) {
    const int ccol = col0 + n0 + j*16 + l16;
    const float bvv = bias[ccol];
#pragma unroll
    for (int i = 0; i < 4; ++i) {
      const int crow = row0 + m0 + i*16 + quad*4;
#pragma unroll
      for (int r = 0; r < 4; ++r)
        C[(size_t)(crow + r)*N + ccol] = acc[i][j][r] + bvv;
    }
  }
}

// ---------------------------------------------------------------------------
// MFMA flash MQA attention, O^T = V^T·P^T formulation — zero P LDS traffic.
// Wave owns 32 queries. S^T = K·Q^T with K-rows read bit2<->bit3 swizzled;
// then lane (h5,l32) holds P^T already in B-operand layout (reg ks*8+j =
// key kg*32+ks*16+h5*8+j of query l32). exp2 softmax, no max (scale*log2e
// folded into Q upstream; |s|<~10 so fp32 exp2 is safe).
// O^T accumulated in C-layout: lane owns query l32 fully -> no Linv LDS,
// packed bf16x4 ctx stores. LDS = Ks+Vs only (35.8 KB -> higher occupancy).
// grid = (T/128, H, B)
// ---------------------------------------------------------------------------
#define KSTR 136
#define VSTR 72
__global__ __launch_bounds__(256) void mqa_attn_mfma(
    const __bf16* __restrict__ qb,   // [B*T][2048] rotated+scaled bf16
    const __bf16* __restrict__ kb,   // [B*T][128]  rotated bf16
    const __bf16* __restrict__ vt,   // [B][128][T] bf16 (V^T)
    __bf16* __restrict__ ctx)        // [B*T][2048] bf16
{
  __shared__ __bf16 Ks[64*KSTR];     // 17408 B
  __shared__ __bf16 Vs[128*VSTR];    // 18432 B
  const int tid = threadIdx.x, lane = tid & 63, wave = tid >> 6;
  const int h5 = lane >> 5, l32 = lane & 31;
  // swap bits 2<->3 of l32: aligns S^T C-layout with P^T B-operand layout
  const int swr = (l32 & 19) | ((l32 & 4) << 1) | ((l32 & 8) >> 1);
  const int h = blockIdx.y, b = blockIdx.z;
  const int qbase = blockIdx.x*128 + wave*32;

  // Q as B-operand fragments: B[k=h5*8+j][n=l32] = Q[q=l32][d=ds*16+h5*8+j]
  bf16x8 qf[8];
  const __bf16* qp = qb + ((size_t)b*T_SEQ + qbase + l32)*DMODEL + h*HDIM;
#pragma unroll
  for (int ds = 0; ds < 8; ++ds) qf[ds] = *(const bf16x8*)(qp + ds*16 + h5*8);

  f32x16 oacc[4];
#pragma unroll
  for (int g = 0; g < 4; ++g)
#pragma unroll
    for (int r = 0; r < 16; ++r) oacc[g][r] = 0.f;
  float lsum = 0.f;

  const __bf16* kbase = kb + (size_t)b*T_SEQ*HDIM;
  const __bf16* vbase = vt + (size_t)b*HDIM*T_SEQ;

  for (int kt = 0; kt < T_SEQ/64; ++kt) {
    __syncthreads();
    // stage K tile: Ks[key][d] (64x128)
#pragma unroll
    for (int i = 0; i < 4; ++i) {
      int idx = i*256 + tid;
      int key = idx >> 4, c = idx & 15;
      *(bf16x8*)&Ks[key*KSTR + c*8] =
          *(const bf16x8*)(kbase + (size_t)(kt*64 + key)*HDIM + c*8);
    }
    // stage V^T tile: Vs[d][key] (128x64)
#pragma unroll
    for (int i = 0; i < 4; ++i) {
      int idx = i*256 + tid;
      int d = idx >> 3, c = idx & 7;
      *(bf16x8*)&Vs[d*VSTR + c*8] =
          *(const bf16x8*)(vbase + (size_t)d*T_SEQ + kt*64 + c*8);
    }
    __syncthreads();

#pragma unroll
    for (int kg = 0; kg < 2; ++kg) {
      // S^T = K·Q^T for 32 keys (row-swizzled K)
      f32x16 sacc;
#pragma unroll
      for (int r = 0; r < 16; ++r) sacc[r] = 0.f;
#pragma unroll
      for (int ds = 0; ds < 8; ++ds) {
        bf16x8 kf = *(const bf16x8*)&Ks[(kg*32 + swr)*KSTR + ds*16 + h5*8];
        sacc = __builtin_amdgcn_mfma_f32_32x32x16_bf16(kf, qf[ds], sacc, 0,0,0);
      }
      // exp2 -> P^T B-operand fragments, in-register
      bf16x8 pf[2];
#pragma unroll
      for (int r = 0; r < 16; ++r) {
        float p = __builtin_amdgcn_exp2f(sacc[r]);
        lsum += p;
        pf[r >> 3][r & 7] = (__bf16)p;
      }
      // O^T += V^T·P^T
#pragma unroll
      for (int ks = 0; ks < 2; ++ks)
#pragma unroll
        for (int g = 0; g < 4; ++g) {
          bf16x8 vf = *(const bf16x8*)&Vs[(g*32 + l32)*VSTR + kg*32 + ks*16 + h5*8];
          oacc[g] = __builtin_amdgcn_mfma_f32_32x32x16_bf16(vf, pf[ks], oacc[g], 0,0,0);
        }
    }
  }

  // lane owns query l32; combine the two h5 halves' key-partials
  lsum += __shfl_xor(lsum, 32);
  const float inv = 1.f / lsum;

  // O^T C-layout: d = g*32 + rq*8 + h5*4 + (reg&3)  -> packed bf16x4 stores
  __bf16* op = ctx + ((size_t)b*T_SEQ + qbase + l32)*DMODEL + h*HDIM;
#pragma unroll
  for (int g = 0; g < 4; ++g)
#pragma unroll
    for (int rq = 0; rq < 4; ++rq) {
      const int d = g*32 + rq*8 + h5*4;
      bf16x4 ov = { (__bf16)(oacc[g][rq*4+0]*inv), (__bf16)(oacc[g][rq*4+1]*inv),
                    (__bf16)(oacc[g][rq*4+2]*inv), (__bf16)(oacc[g][rq*4+3]*inv) };
      *(bf16x4*)&op[d] = ov;
    }
}

// ---------------------------------------------------------------------------
extern "C" void kernel_launch(void* const* d_in, const int* in_sizes, int n_in,
                              void* d_out, int out_size, void* d_ws, size_t ws_size,
                              hipStream_t stream) {
  const float* x  = (const float*)d_in[0];
  const float* Wq = (const float*)d_in[1];
  const float* bq = (const float*)d_in[2];
  const float* Wk = (const float*)d_in[3];
  const float* bk = (const float*)d_in[4];
  const float* Wv = (const float*)d_in[5];
  const float* bv = (const float*)d_in[6];
  const float* Wo = (const float*)d_in[7];
  const float* bo = (const float*)d_in[8];
  float* out = (float*)d_out;

  uint8_t* ws = (uint8_t*)d_ws;
  __bf16* qrb  = (__bf16*)(ws);              // 16.78 MB rotated+scaled Q bf16
  __bf16* xb   = (__bf16*)(ws + 16777216);   // 16.78 MB x bf16; later ctx bf16
  __bf16* wqkvt= (__bf16*)(ws + 33554432);   //  9.44 MB [2304][2048]
  __bf16* wot  = (__bf16*)(ws + 42991616);   //  8.39 MB [2048][2048]
  __bf16* kbb  = (__bf16*)(ws + 51380224);   //  1.05 MB rotated K bf16
  __bf16* vbb  = (__bf16*)(ws + 52428800);   //  1.05 MB V bf16 [4096][128]
  __bf16* vtb  = (__bf16*)(ws + 53477376);   //  1.05 MB V^T bf16 [B][128][T]
  float2* rope = (float2*)(ws + 54525952);   //  1.05 MB cos/sin table

  const float qscale = 1.4426950408889634f * 0.08838834764831845f; // log2e/sqrt(128)

  build_rope_kernel<<<512, 256, 0, stream>>>(rope);
  wtrans_kernel<<<dim3(136,64), 256, 0, stream>>>(Wq, Wk, Wv, Wo, wqkvt, wot);
  cast_bf16_kernel<<<8192, 256, 0, stream>>>(x, xb, MROWS*DMODEL/4);

  gemm_qkv_fused<<<dim3(18,32), 256, 0, stream>>>(
      xb, wqkvt, bq, bk, bv, rope, qrb, kbb, vbb, qscale);

  transpose_v_kernel<<<dim3(4,64,2), 256, 0, stream>>>(vbb, vtb);

  // attention reads qrb/kbb/vtb, writes bf16 ctx over xb (x is dead)
  mqa_attn_mfma<<<dim3(16,16,2), 256, 0, stream>>>(qrb, kbb, vtb, xb);

  gemm_bf16_t128<<<dim3(16,32), 256, 0, stream>>>(xb, wot, bo, out, MROWS, DMODEL, DMODEL);
}

// Round 6
// 322.390 us; speedup vs baseline: 1.1187x; 1.1187x over previous
//
#include <hip/hip_runtime.h>
#include <math.h>

#define T_SEQ  2048
#define DMODEL 2048
#define NHEADS 16
#define HDIM   128
#define MROWS  4096   // B*T

typedef __attribute__((ext_vector_type(8)))  __bf16 bf16x8;
typedef __attribute__((ext_vector_type(4)))  __bf16 bf16x4;
typedef __attribute__((ext_vector_type(4)))  float  f32x4;
typedef __attribute__((ext_vector_type(16))) float  f32x16;

#define GLOBAL_AS __attribute__((address_space(1)))
#define LDS_AS    __attribute__((address_space(3)))
__device__ __forceinline__ void async_copy16(const __bf16* g, __bf16* l) {
  // 16B/lane, LDS dest = wave-uniform base + lane*16 (m97/m104 semantics)
  __builtin_amdgcn_global_load_lds((const GLOBAL_AS void*)g, (LDS_AS void*)l, 16, 0, 0);
}

// ---------------------------------------------------------------------------
// RoPE table: rope[pos*64+d] = {cos, sin}. fp64 trig (one-time, 131k entries).
// ---------------------------------------------------------------------------
__global__ void build_rope_kernel(float2* __restrict__ rope) {
  int idx = blockIdx.x * blockDim.x + threadIdx.x;   // 2048*64
  int d = idx & 63, pos = idx >> 6;
  double freq = pow(10000.0, -(double)d / 64.0);
  double ang = (double)pos * freq;
  rope[idx] = make_float2((float)cos(ang), (float)sin(ang));
}

// ---------------------------------------------------------------------------
// fp32 -> bf16 cast
// ---------------------------------------------------------------------------
__global__ void cast_bf16_kernel(const float* __restrict__ in,
                                 __bf16* __restrict__ out, int n4) {
  int i = blockIdx.x * blockDim.x + threadIdx.x;
  if (i >= n4) return;
  float4 v = ((const float4*)in)[i];
  bf16x4 o = { (__bf16)v.x, (__bf16)v.y, (__bf16)v.z, (__bf16)v.w };
  *(bf16x4*)(out + (size_t)i*4) = o;
}

// ---------------------------------------------------------------------------
// Combined weight transpose-cast: Wq|Wk|Wv -> wqkvt [2304][2048],
// Wo -> wot [2048][2048]. One launch, region by blockIdx.x.
// ---------------------------------------------------------------------------
__global__ void wtrans_kernel(const float* __restrict__ Wq,
                              const float* __restrict__ Wk,
                              const float* __restrict__ Wv,
                              const float* __restrict__ Wo,
                              __bf16* __restrict__ wqkvt,
                              __bf16* __restrict__ wot) {
  __shared__ float t[32][33];
  const int bx = blockIdx.x;            // 0..135
  const float* src; __bf16* dst; int istride, c0, orow;
  if (bx < 64)       { src = Wq; istride = 2048; c0 = bx*32;      orow = c0;        dst = wqkvt; }
  else if (bx < 68)  { src = Wk; istride = 128;  c0 = (bx-64)*32; orow = 2048 + c0; dst = wqkvt; }
  else if (bx < 72)  { src = Wv; istride = 128;  c0 = (bx-68)*32; orow = 2176 + c0; dst = wqkvt; }
  else               { src = Wo; istride = 2048; c0 = (bx-72)*32; orow = c0;        dst = wot; }
  const int tx = threadIdx.x & 31, ty = threadIdx.x >> 5;
  const int r0 = blockIdx.y*32;
#pragma unroll
  for (int i = 0; i < 4; ++i)
    t[ty + i*8][tx] = src[(size_t)(r0 + ty + i*8)*istride + c0 + tx];
  __syncthreads();
#pragma unroll
  for (int i = 0; i < 4; ++i)
    dst[(size_t)(orow + ty + i*8)*2048 + r0 + tx] = (__bf16)t[tx][ty + i*8];
}

// ---------------------------------------------------------------------------
// bf16 -> bf16 transpose for V: in [B][2048][128] -> out [B][128][2048].
// ---------------------------------------------------------------------------
__global__ void transpose_v_kernel(const __bf16* __restrict__ in,
                                   __bf16* __restrict__ out) {
  __shared__ __bf16 t[32][34];
  const int bz = blockIdx.z;
  in  += (size_t)bz * 2048 * 128;
  out += (size_t)bz * 128 * 2048;
  const int tx = threadIdx.x & 31, ty = threadIdx.x >> 5;
  const int r0 = blockIdx.y*32, c0 = blockIdx.x*32;
#pragma unroll
  for (int i = 0; i < 4; ++i)
    t[ty + i*8][tx] = in[(size_t)(r0 + ty + i*8)*128 + c0 + tx];
  __syncthreads();
#pragma unroll
  for (int i = 0; i < 4; ++i)
    out[(size_t)(c0 + ty + i*8)*2048 + r0 + tx] = t[tx][ty + i*8];
}

// ---------------------------------------------------------------------------
// Fused QKV GEMM: C = x @ [Wq|Wk|Wv] + bias, then RoPE (Q,K) + scale (Q) +
// bf16 cast, all register-resident in the epilogue (column remap puts the
// RoPE pair (d, d+64) in the same lane). m97-style K-loop.
// grid (18, 32): bx 0..15 = Q head bx; bx 16 = K; bx 17 = V.
// ---------------------------------------------------------------------------
__global__ __launch_bounds__(256) void gemm_qkv_fused(
    const __bf16* __restrict__ A,      // xb [4096][2048]
    const __bf16* __restrict__ Bt,     // wqkvt [2304][2048]
    const float* __restrict__ bq, const float* __restrict__ bk,
    const float* __restrict__ bv,
    const float2* __restrict__ rope,   // [2048][64]
    __bf16* __restrict__ qrb,          // [4096][2048]
    __bf16* __restrict__ kbb,          // [4096][128]
    __bf16* __restrict__ vbb,          // [4096][128]
    float qscale)
{
  __shared__ __bf16 As[128*32];
  __shared__ __bf16 Bs[128*32];
  const int tid = threadIdx.x;
  const int lane = tid & 63, wave = tid >> 6;
  const int quad = lane >> 4, l16 = lane & 15;
  const int m0 = (wave >> 1)*64, n0 = (wave & 1)*32;
  const int row0 = blockIdx.y*128, col0 = blockIdx.x*128;
  const int srow = lane >> 2, scol = (lane & 3)*8;

  f32x4 acc[4][4];
#pragma unroll
  for (int i = 0; i < 4; ++i)
#pragma unroll
    for (int j = 0; j < 4; ++j) acc[i][j] = (f32x4){0.f,0.f,0.f,0.f};

  const __bf16* Ag = A  + (size_t)(row0 + wave*32 + srow)*DMODEL + scol;
  const __bf16* Bg = Bt + (size_t)(col0 + wave*32 + srow)*DMODEL + scol;
  __bf16* AsW = &As[wave*1024];
  __bf16* BsW = &Bs[wave*1024];

  for (int kk = 0; kk < DMODEL; kk += 32) {
    __syncthreads();
    async_copy16(Ag + kk,                     AsW);
    async_copy16(Ag + kk + (size_t)16*DMODEL, AsW + 512);
    async_copy16(Bg + kk,                     BsW);
    async_copy16(Bg + kk + (size_t)16*DMODEL, BsW + 512);
    __syncthreads();
    bf16x8 af[4], bfr[4];
#pragma unroll
    for (int i = 0; i < 4; ++i)
      af[i] = *(const bf16x8*)&As[(m0 + i*16 + l16)*32 + quad*8];
#pragma unroll
    for (int j = 0; j < 4; ++j) {
      const int cb = n0 + (j & 1)*16 + (j >> 1)*64;   // remapped column base
      bfr[j] = *(const bf16x8*)&Bs[(cb + l16)*32 + quad*8];
    }
#pragma unroll
    for (int i = 0; i < 4; ++i)
#pragma unroll
      for (int j = 0; j < 4; ++j)
        acc[i][j] = __builtin_amdgcn_mfma_f32_16x16x32_bf16(af[i], bfr[j], acc[i][j], 0,0,0);
  }

  // ---- fused epilogue: bias + RoPE + scale + bf16 store -------------------
  const int bx = blockIdx.x;
  const float* bias_p; float scale; bool rot; __bf16* obase; int ostride;
  if (bx < 16)      { bias_p = bq + bx*128; scale = qscale; rot = true;
                      obase = qrb + bx*128; ostride = 2048; }
  else if (bx == 16){ bias_p = bk; scale = 1.f; rot = true;
                      obase = kbb; ostride = 128; }
  else              { bias_p = bv; scale = 1.f; rot = false;
                      obase = vbb; ostride = 128; }

#pragma unroll
  for (int j = 0; j < 2; ++j) {
    const int d = n0 + j*16 + l16;        // 0..63 within the 128-wide region
    const float b1 = bias_p[d], b2 = bias_p[d + 64];
#pragma unroll
    for (int i = 0; i < 4; ++i) {
      const int rl = m0 + i*16 + quad*4;
#pragma unroll
      for (int r = 0; r < 4; ++r) {
        const int rg = row0 + rl + r;
        const float x1 = acc[i][j][r]   + b1;
        const float x2 = acc[i][j+2][r] + b2;
        float c = 1.f, s = 0.f;
        if (rot) { float2 cs = rope[(size_t)(rg & (T_SEQ-1))*64 + d]; c = cs.x; s = cs.y; }
        obase[(size_t)rg*ostride + d]      = (__bf16)((x1*c - x2*s)*scale);
        obase[(size_t)rg*ostride + d + 64] = (__bf16)((x2*c + x1*s)*scale);
      }
    }
  }
}

// ---------------------------------------------------------------------------
// m97-style bf16 MFMA GEMM: C = A@B + bias, fp32 out (O projection).
// ---------------------------------------------------------------------------
__global__ __launch_bounds__(256) void gemm_bf16_t128(
    const __bf16* __restrict__ A, const __bf16* __restrict__ Bt,
    const float* __restrict__ bias, float* __restrict__ C,
    int M, int N, int K)
{
  __shared__ __bf16 As[128*32];
  __shared__ __bf16 Bs[128*32];
  const int tid = threadIdx.x;
  const int lane = tid & 63, wave = tid >> 6;
  const int quad = lane >> 4, l16 = lane & 15;
  const int m0 = (wave & 1)*64, n0 = (wave >> 1)*64;
  const int row0 = blockIdx.y*128, col0 = blockIdx.x*128;
  const int srow = lane >> 2, scol = (lane & 3)*8;

  f32x4 acc[4][4];
#pragma unroll
  for (int i = 0; i < 4; ++i)
#pragma unroll
    for (int j = 0; j < 4; ++j) acc[i][j] = (f32x4){0.f,0.f,0.f,0.f};

  const __bf16* Ag = A  + (size_t)(row0 + wave*32 + srow)*K + scol;
  const __bf16* Bg = Bt + (size_t)(col0 + wave*32 + srow)*K + scol;
  __bf16* AsW = &As[wave*1024];
  __bf16* BsW = &Bs[wave*1024];

  for (int kk = 0; kk < K; kk += 32) {
    __syncthreads();
    async_copy16(Ag + kk,              AsW);
    async_copy16(Ag + kk + (size_t)16*K, AsW + 512);
    async_copy16(Bg + kk,              BsW);
    async_copy16(Bg + kk + (size_t)16*K, BsW + 512);
    __syncthreads();
    bf16x8 af[4], bfr[4];
#pragma unroll
    for (int i = 0; i < 4; ++i)
      af[i] = *(const bf16x8*)&As[(m0 + i*16 + l16)*32 + quad*8];
#pragma unroll
    for (int j = 0; j < 4; ++j)
      bfr[j] = *(const bf16x8*)&Bs[(n0 + j*16 + l16)*32 + quad*8];
#pragma unroll
    for (int i = 0; i < 4; ++i)
#pragma unroll
      for (int j = 0; j < 4; ++j)
        acc[i][j] = __builtin_amdgcn_mfma_f32_16x16x32_bf16(af[i], bfr[j], acc[i][j], 0,0,0);
  }
#pragma unroll
  for (int j = 0; j < 4; ++j) {
    const int ccol = col0 + n0 + j*16 + l16;
    const float bvv = bias[ccol];
#pragma unroll
    for (int i = 0; i < 4; ++i) {
      const int crow = row0 + m0 + i*16 + quad*4;
#pragma unroll
      for (int r = 0; r < 4; ++r)
        C[(size_t)(crow + r)*N + ccol] = acc[i][j][r] + bvv;
    }
  }
}

// ---------------------------------------------------------------------------
// MFMA flash MQA attention, O^T = V^T·P^T, in-register P^T (R5 swizzle trick,
// HW-verified) + R6 scheduling fixes:
//  * S-phase: 4 INDEPENDENT MFMA chains of length 4 (ds split 0-3/4-7 into
//    separate accumulators, summed before exp2) — was 1 serial chain of 16.
//  * O-phase: 4 independent oacc[g] chains of length 4.
//  * K/V global->reg prefetch of tile t+1 issued before compute of tile t.
// grid = (T/128, H, B); occupancy grid-limited at 2 blocks/CU.
// ---------------------------------------------------------------------------
#define KSTR 136
#define VSTR 72
__global__ __launch_bounds__(256) void mqa_attn_mfma(
    const __bf16* __restrict__ qb,   // [B*T][2048] rotated+scaled bf16
    const __bf16* __restrict__ kb,   // [B*T][128]  rotated bf16
    const __bf16* __restrict__ vt,   // [B][128][T] bf16 (V^T)
    __bf16* __restrict__ ctx)        // [B*T][2048] bf16
{
  __shared__ __bf16 Ks[64*KSTR];     // 17408 B
  __shared__ __bf16 Vs[128*VSTR];    // 18432 B
  const int tid = threadIdx.x, lane = tid & 63, wave = tid >> 6;
  const int h5 = lane >> 5, l32 = lane & 31;
  // swap bits 2<->3 of l32: aligns S^T C-layout with P^T B-operand layout
  const int swr = (l32 & 19) | ((l32 & 4) << 1) | ((l32 & 8) >> 1);
  const int h = blockIdx.y, b = blockIdx.z;
  const int qbase = blockIdx.x*128 + wave*32;

  // Q as B-operand fragments: B[k=h5*8+j][n=l32] = Q[q=l32][d=ds*16+h5*8+j]
  bf16x8 qf[8];
  const __bf16* qp = qb + ((size_t)b*T_SEQ + qbase + l32)*DMODEL + h*HDIM;
#pragma unroll
  for (int ds = 0; ds < 8; ++ds) qf[ds] = *(const bf16x8*)(qp + ds*16 + h5*8);

  f32x16 oacc[4];
#pragma unroll
  for (int g = 0; g < 4; ++g)
#pragma unroll
    for (int r = 0; r < 16; ++r) oacc[g][r] = 0.f;
  float lsum = 0.f;

  const __bf16* kbase = kb + (size_t)b*T_SEQ*HDIM;
  const __bf16* vbase = vt + (size_t)b*HDIM*T_SEQ;

  // per-thread staging coordinates (4 chunks K, 4 chunks V per tile)
  const int kkey = tid >> 2;                 // with i*64 offset: keys
  const int kcol = (tid & 3)*32;             // 4 chunks of 8 along d... no:
  // K: chunk idx = i*256+tid -> key=(i*256+tid)>>4, c=(i*256+tid)&15
  // V: chunk idx = i*256+tid -> d=(i*256+tid)>>3,  c=(i*256+tid)&7

  bf16x8 kreg[4], vreg[4];
  // prologue: load tile 0
#pragma unroll
  for (int i = 0; i < 4; ++i) {
    int idx = i*256 + tid;
    kreg[i] = *(const bf16x8*)(kbase + (size_t)(idx >> 4)*HDIM + (idx & 15)*8);
    vreg[i] = *(const bf16x8*)(vbase + (size_t)(idx >> 3)*T_SEQ + (idx & 7)*8);
  }

  constexpr int NT = T_SEQ/64;
  for (int kt = 0; kt < NT; ++kt) {
    __syncthreads();                   // previous compute done with Ks/Vs
    // store prefetched tile to LDS
#pragma unroll
    for (int i = 0; i < 4; ++i) {
      int idx = i*256 + tid;
      *(bf16x8*)&Ks[(idx >> 4)*KSTR + (idx & 15)*8] = kreg[i];
      *(bf16x8*)&Vs[(idx >> 3)*VSTR + (idx & 7)*8]  = vreg[i];
    }
    __syncthreads();
    // prefetch tile kt+1 (wraps to 0 on last iter; always in-bounds)
    {
      const int ktn = (kt + 1 < NT) ? kt + 1 : 0;
#pragma unroll
      for (int i = 0; i < 4; ++i) {
        int idx = i*256 + tid;
        kreg[i] = *(const bf16x8*)(kbase + (size_t)(ktn*64 + (idx >> 4))*HDIM + (idx & 15)*8);
        vreg[i] = *(const bf16x8*)(vbase + (size_t)(idx >> 3)*T_SEQ + ktn*64 + (idx & 7)*8);
      }
    }

    // ---- S phase: 4 independent chains of 4 dependent MFMAs ----
    f32x16 s_lo[2], s_hi[2];
#pragma unroll
    for (int kg = 0; kg < 2; ++kg)
#pragma unroll
      for (int r = 0; r < 16; ++r) { s_lo[kg][r] = 0.f; s_hi[kg][r] = 0.f; }
#pragma unroll
    for (int ds = 0; ds < 4; ++ds) {
      bf16x8 k00 = *(const bf16x8*)&Ks[swr*KSTR        + ds*16 + h5*8];
      bf16x8 k01 = *(const bf16x8*)&Ks[(32+swr)*KSTR   + ds*16 + h5*8];
      bf16x8 k10 = *(const bf16x8*)&Ks[swr*KSTR        + (ds+4)*16 + h5*8];
      bf16x8 k11 = *(const bf16x8*)&Ks[(32+swr)*KSTR   + (ds+4)*16 + h5*8];
      s_lo[0] = __builtin_amdgcn_mfma_f32_32x32x16_bf16(k00, qf[ds],   s_lo[0], 0,0,0);
      s_lo[1] = __builtin_amdgcn_mfma_f32_32x32x16_bf16(k01, qf[ds],   s_lo[1], 0,0,0);
      s_hi[0] = __builtin_amdgcn_mfma_f32_32x32x16_bf16(k10, qf[ds+4], s_hi[0], 0,0,0);
      s_hi[1] = __builtin_amdgcn_mfma_f32_32x32x16_bf16(k11, qf[ds+4], s_hi[1], 0,0,0);
    }

    // ---- exp2 -> P^T B-operand fragments, in-register ----
    bf16x8 pf[2][2];
#pragma unroll
    for (int kg = 0; kg < 2; ++kg)
#pragma unroll
      for (int r = 0; r < 16; ++r) {
        float p = __builtin_amdgcn_exp2f(s_lo[kg][r] + s_hi[kg][r]);
        lsum += p;
        pf[kg][r >> 3][r & 7] = (__bf16)p;
      }

    // ---- O phase: 4 independent oacc chains ----
#pragma unroll
    for (int kg = 0; kg < 2; ++kg)
#pragma unroll
      for (int ks = 0; ks < 2; ++ks) {
#pragma unroll
        for (int g = 0; g < 4; ++g) {
          bf16x8 vf = *(const bf16x8*)&Vs[(g*32 + l32)*VSTR + kg*32 + ks*16 + h5*8];
          oacc[g] = __builtin_amdgcn_mfma_f32_32x32x16_bf16(vf, pf[kg][ks], oacc[g], 0,0,0);
        }
      }
  }

  // lane owns query l32; combine the two h5 halves' key-partials
  lsum += __shfl_xor(lsum, 32);
  const float inv = 1.f / lsum;

  // O^T C-layout: d = g*32 + rq*8 + h5*4 + (reg&3)  -> packed bf16x4 stores
  __bf16* op = ctx + ((size_t)b*T_SEQ + qbase + l32)*DMODEL + h*HDIM;
#pragma unroll
  for (int g = 0; g < 4; ++g)
#pragma unroll
    for (int rq = 0; rq < 4; ++rq) {
      const int d = g*32 + rq*8 + h5*4;
      bf16x4 ov = { (__bf16)(oacc[g][rq*4+0]*inv), (__bf16)(oacc[g][rq*4+1]*inv),
                    (__bf16)(oacc[g][rq*4+2]*inv), (__bf16)(oacc[g][rq*4+3]*inv) };
      *(bf16x4*)&op[d] = ov;
    }
}

// ---------------------------------------------------------------------------
extern "C" void kernel_launch(void* const* d_in, const int* in_sizes, int n_in,
                              void* d_out, int out_size, void* d_ws, size_t ws_size,
                              hipStream_t stream) {
  const float* x  = (const float*)d_in[0];
  const float* Wq = (const float*)d_in[1];
  const float* bq = (const float*)d_in[2];
  const float* Wk = (const float*)d_in[3];
  const float* bk = (const float*)d_in[4];
  const float* Wv = (const float*)d_in[5];
  const float* bv = (const float*)d_in[6];
  const float* Wo = (const float*)d_in[7];
  const float* bo = (const float*)d_in[8];
  float* out = (float*)d_out;

  uint8_t* ws = (uint8_t*)d_ws;
  __bf16* qrb  = (__bf16*)(ws);              // 16.78 MB rotated+scaled Q bf16
  __bf16* xb   = (__bf16*)(ws + 16777216);   // 16.78 MB x bf16; later ctx bf16
  __bf16* wqkvt= (__bf16*)(ws + 33554432);   //  9.44 MB [2304][2048]
  __bf16* wot  = (__bf16*)(ws + 42991616);   //  8.39 MB [2048][2048]
  __bf16* kbb  = (__bf16*)(ws + 51380224);   //  1.05 MB rotated K bf16
  __bf16* vbb  = (__bf16*)(ws + 52428800);   //  1.05 MB V bf16 [4096][128]
  __bf16* vtb  = (__bf16*)(ws + 53477376);   //  1.05 MB V^T bf16 [B][128][T]
  float2* rope = (float2*)(ws + 54525952);   //  1.05 MB cos/sin table

  const float qscale = 1.4426950408889634f * 0.08838834764831845f; // log2e/sqrt(128)

  build_rope_kernel<<<512, 256, 0, stream>>>(rope);
  wtrans_kernel<<<dim3(136,64), 256, 0, stream>>>(Wq, Wk, Wv, Wo, wqkvt, wot);
  cast_bf16_kernel<<<8192, 256, 0, stream>>>(x, xb, MROWS*DMODEL/4);

  gemm_qkv_fused<<<dim3(18,32), 256, 0, stream>>>(
      xb, wqkvt, bq, bk, bv, rope, qrb, kbb, vbb, qscale);

  transpose_v_kernel<<<dim3(4,64,2), 256, 0, stream>>>(vbb, vtb);

  // attention reads qrb/kbb/vtb, writes bf16 ctx over xb (x is dead)
  mqa_attn_mfma<<<dim3(16,16,2), 256, 0, stream>>>(qrb, kbb, vtb, xb);

  gemm_bf16_t128<<<dim3(16,32), 256, 0, stream>>>(xb, wot, bo, out, MROWS, DMODEL, DMODEL);
}